// Round 5
// baseline (361.273 us; speedup 1.0000x reference)
//
#include <hip/hip_runtime.h>
#include <hip/hip_bf16.h>

typedef short short8 __attribute__((ext_vector_type(8)));
typedef float float4v __attribute__((ext_vector_type(4)));

#define TK 32
#define MAXSPLIT 16
#define APAD 40   // 80 B row stride for bf16 tiles: 2-way-max bank aliasing on b128 frag reads

__device__ __forceinline__ unsigned int bfrne(float f) {
    unsigned int u = __builtin_bit_cast(unsigned int, f);
    return (u + 0x7fffu + ((u >> 16) & 1u)) >> 16;   // RNE
}
__device__ __forceinline__ unsigned int pack2bf(float a, float b) {
    return bfrne(a) | (bfrne(b) << 16);
}

// ---------------- K1: split-K bf16 MFMA GEMM: P_mod[b][j] = sum_k A[b,k] * W[j,k] ----------------
// 128x128 tiles, 4 waves of 64x64, BK=32, double-buffered bf16 LDS for BOTH operands.
// Staging: full-128B-line global_load_dwordx4 (8 lanes/row-chunk) -> bf16 pack -> padded LDS.
// No outstanding vm ops at the barrier: loads are consumed by the pack/store pre-barrier,
// so the barrier's vmcnt(0) drain is a no-op and the prefetch window = full compute phase.
__global__ __launch_bounds__(256, 3) void gemm_kernel(
    const float* __restrict__ Ae, const float* __restrict__ Am, const float* __restrict__ Ac,
    const float* __restrict__ Wex, const float* __restrict__ Wey,
    const float* __restrict__ Wmx, const float* __restrict__ Wmy,
    const float* __restrict__ Wcx, const float* __restrict__ Wcy,
    float* __restrict__ part, int nsplit)
{
    // XCD grouping: xcd = bid&7 gets a contiguous job range -> 16-tile (mod,split) groups
    // co-resident on one XCD for L2 slab reuse.
    int nb = gridDim.x;                 // 48*nsplit, divisible by 8
    int per = nb >> 3;
    int bid = blockIdx.x;
    int job = (bid & 7) * per + (bid >> 3);

    int mod = job / (16 * nsplit);
    int rem = job - mod * 16 * nsplit;
    int split = rem >> 4;
    int t2 = rem & 15;
    int ti = t2 >> 2, tj = t2 & 3;

    const float* A; const float* Wx; const float* Wy; int K;
    if (mod == 0)      { A = Ae; Wx = Wex; Wy = Wey; K = 20000; }
    else if (mod == 1) { A = Am; Wx = Wmx; Wy = Wmy; K = 15000; }
    else               { A = Ac; Wx = Wcx; Wy = Wcy; K = 20000; }

    int chunk = ((K + nsplit * TK - 1) / (nsplit * TK)) * TK;
    int kstart = split * chunk;
    int kend = kstart + chunk; if (kend > K) kend = K;
    int nstep = (kend - kstart + TK - 1) / TK;

    const float* Abase = A + (size_t)(ti * 128) * K;
    const float* Wbase = (tj < 2) ? (Wx + (size_t)(tj * 128) * K)
                                  : (Wy + (size_t)((tj - 2) * 128) * K);

    __shared__ unsigned short As[2][128][APAD];   // bf16, padded
    __shared__ unsigned short Bs[2][128][APAD];   // bf16, padded

    int tid = threadIdx.x;
    int lane = tid & 63, w = tid >> 6;
    int wr = (w >> 1) * 64, wc = (w & 1) * 64;
    int r16 = lane & 15, q8 = (lane >> 4) * 8;

    // Staging: inst i covers row i*32 + tid>>3, col granule (tid&7)*4 (full 128B lines / 8 lanes)
    int ra0 = tid >> 3;
    int ca  = (tid & 7) * 4;

    float4v ar[4], br[4];
    auto loadAB = [&](int k0) {
        int k = k0 + ca; if (k > K - 4) k = K - 4;       // clamp; tail zeroed at store
        #pragma unroll
        for (int i = 0; i < 4; ++i) {
            ar[i] = *(const float4v*)(Abase + (size_t)(ra0 + i * 32) * K + k);
            br[i] = *(const float4v*)(Wbase + (size_t)(ra0 + i * 32) * K + k);
        }
    };
    auto storeAB = [&](int buf, int k0, bool tail) {
        bool kill = tail && (k0 + ca >= kend);
        #pragma unroll
        for (int i = 0; i < 4; ++i) {
            float4v va = ar[i], vb = br[i];
            if (kill) { va = (float4v){0.f,0.f,0.f,0.f}; vb = (float4v){0.f,0.f,0.f,0.f}; }
            uint2 pa, pb;
            pa.x = pack2bf(va[0], va[1]); pa.y = pack2bf(va[2], va[3]);
            pb.x = pack2bf(vb[0], vb[1]); pb.y = pack2bf(vb[2], vb[3]);
            *(uint2*)&As[buf][ra0 + i * 32][ca] = pa;
            *(uint2*)&Bs[buf][ra0 + i * 32][ca] = pb;
        }
    };

    float4v acc[4][4];
    #pragma unroll
    for (int a = 0; a < 4; ++a)
        #pragma unroll
        for (int b = 0; b < 4; ++b)
            acc[a][b] = (float4v){0.f, 0.f, 0.f, 0.f};

    auto computeStep = [&](int buf) {
        short8 fa[4], fb[4];
        #pragma unroll
        for (int a = 0; a < 4; ++a)
            fa[a] = *(const short8*)&As[buf][wr + a * 16 + r16][q8];
        #pragma unroll
        for (int b = 0; b < 4; ++b)
            fb[b] = *(const short8*)&Bs[buf][wc + b * 16 + r16][q8];
        #pragma unroll
        for (int a = 0; a < 4; ++a)
            #pragma unroll
            for (int b = 0; b < 4; ++b)
                acc[a][b] = __builtin_amdgcn_mfma_f32_16x16x32_bf16(fa[a], fb[b], acc[a][b], 0, 0, 0);
    };

    // prologue: stage step 0
    loadAB(kstart);
    storeAB(0, kstart, kstart + TK > kend);

    for (int s = 0; s < nstep; ++s) {
        int cur = s & 1;
        int k1 = kstart + (s + 1) * TK;
        bool more = (s + 1 < nstep);
        __syncthreads();                 // buf[cur] stores visible; prev reads of cur^1 done
        if (more) loadAB(k1);            // in flight across the whole compute phase
        computeStep(cur);
        if (more) storeAB(cur ^ 1, k1, k1 + TK > kend);
    }

    // partial tile out: part[mod][t2][split][128][128]
    float* pbase = part + (size_t)((mod * 16 + t2) * nsplit + split) * 16384;
    #pragma unroll
    for (int a = 0; a < 4; ++a)
        #pragma unroll
        for (int b = 0; b < 4; ++b)
            #pragma unroll
            for (int r = 0; r < 4; ++r) {
                int row = wr + a * 16 + (lane >> 4) * 4 + r;  // C/D: row = quad*4+reg
                int col = wc + b * 16 + r16;                   // col = lane&15
                pbase[row * 128 + col] = acc[a][b][r];
            }
}

// ---------------- K2: split-K reduction + zero head accumulators ----------------
__global__ void reduce_kernel(const float* __restrict__ part, float* __restrict__ P,
                              float* __restrict__ headacc, int nsplit)
{
    int gid = blockIdx.x * 256 + threadIdx.x;   // 786432 total
    if (gid < 1536) headacc[gid] = 0.f;
    int mod = gid >> 18;
    int rem = gid & 262143;
    int b = rem >> 9, j = rem & 511;
    int ti = b >> 7, r = b & 127, tj = j >> 7, c = j & 127;
    int t2 = ti * 4 + tj;
    const float* src = part + (size_t)((mod * 16 + t2) * nsplit) * 16384 + r * 128 + c;
    float s = 0.f;
    for (int k = 0; k < nsplit; ++k) s += src[(size_t)k * 16384];
    P[gid] = s;
}

// ---------------- K3: per-(batch,pair) fused normalize + rank-2 attention + head partials ----------------
__global__ __launch_bounds__(256) void pairs_kernel(
    const float* __restrict__ P, float* __restrict__ headacc,
    const float* __restrict__ W3e, const float* __restrict__ W3m, const float* __restrict__ W3c)
{
    int b = blockIdx.x / 3, pair = blockIdx.x % 3;   // 0:em 1:ec 2:mc
    int t = threadIdx.x;
    __shared__ float2 Pn[256], Qn[256];
    __shared__ float Rinv[256];
    __shared__ float red[4];

    int pm = (pair == 2) ? 1 : 0;
    int qm = (pair == 0) ? 1 : 2;
    const float* prow = P + pm * 262144 + b * 512;
    const float* qrow = P + qm * 262144 + b * 512;

    float px = prow[t], py = prow[256 + t];
    float ip = rsqrtf(px * px + py * py);
    Pn[t] = (float2){px * ip, py * ip};
    float qx = qrow[t], qy = qrow[256 + t];
    float iq = rsqrtf(qx * qx + qy * qy);
    Qn[t] = (float2){qx * iq, qy * iq};
    __syncthreads();

    const float L2E = 1.4426950408889634f;

    // ---- pass R: thread = row r. rowsum + q-weighted row sums -> B-side output (q's feature) ----
    float pxr = Pn[t].x * L2E, pyr = Pn[t].y * L2E;
    float rs = 0.f, rqx = 0.f, rqy = 0.f;
    #pragma unroll 4
    for (int j = 0; j < 256; ++j) {
        float2 qv = Qn[j];
        float x = exp2f(fmaf(pyr, qv.y, pxr * qv.x));
        rs += x;
        rqx = fmaf(qv.x, x, rqx);
        rqy = fmaf(qv.y, x, rqy);
    }
    float rinv = 1.f / rs;
    Rinv[t] = rinv;
    float Fq0 = rqx * rinv, Fq1 = rqy * rinv;

    const float* WR; int hR, offR;
    if (pair == 0)      { WR = W3m; hR = 1; offR = 0; }   // m_feat chunks 0,1
    else if (pair == 1) { WR = W3c; hR = 2; offR = 0; }   // c_feat chunks 0,1
    else                { WR = W3c; hR = 2; offR = 512; } // c_feat chunks 2,3
    float v = Fq0 * WR[offR + t] + Fq1 * WR[offR + 256 + t];
    #pragma unroll
    for (int o = 32; o > 0; o >>= 1) v += __shfl_down(v, o, 64);
    if ((t & 63) == 0) red[t >> 6] = v;
    __syncthreads();
    if (t == 0) atomicAdd(&headacc[b * 3 + hR], red[0] + red[1] + red[2] + red[3]);
    __syncthreads();

    // ---- pass C: thread = col n. col softmax (A-side) or rowsum-prescaled matmul (mc C-form) ----
    float qxr = Qn[t].x * L2E, qyr = Qn[t].y * L2E;
    float cs = 0.f, cpx = 0.f, cpy = 0.f;
    if (pair < 2) {
        #pragma unroll 4
        for (int i = 0; i < 256; ++i) {
            float2 pv = Pn[i];
            float x = exp2f(fmaf(qyr, pv.y, qxr * pv.x));
            cs += x;
            cpx = fmaf(pv.x, x, cpx);
            cpy = fmaf(pv.y, x, cpy);
        }
        float ci = 1.f / cs;
        cpx *= ci; cpy *= ci;
    } else {
        #pragma unroll 4
        for (int i = 0; i < 256; ++i) {
            float2 pv = Pn[i];
            float x = exp2f(fmaf(qyr, pv.y, qxr * pv.x)) * Rinv[i];
            cpx = fmaf(pv.x, x, cpx);
            cpy = fmaf(pv.y, x, cpy);
        }
    }
    const float* WC; int hC, offC;
    if (pair == 0)      { WC = W3e; hC = 0; offC = 0; }   // e_feat chunks 0,1
    else if (pair == 1) { WC = W3e; hC = 0; offC = 512; } // e_feat chunks 2,3
    else                { WC = W3m; hC = 1; offC = 512; } // m_feat chunks 2,3
    float v2 = cpx * WC[offC + t] + cpy * WC[offC + 256 + t];
    #pragma unroll
    for (int o = 32; o > 0; o >>= 1) v2 += __shfl_down(v2, o, 64);
    if ((t & 63) == 0) red[t >> 6] = v2;
    __syncthreads();
    if (t == 0) atomicAdd(&headacc[b * 3 + hC], red[0] + red[1] + red[2] + red[3]);
}

// ---------------- K4: bias + sigmoid ----------------
__global__ void head_kernel(const float* __restrict__ headacc,
                            const float* __restrict__ b3e, const float* __restrict__ b3m,
                            const float* __restrict__ b3c, float* __restrict__ out)
{
    int i = blockIdx.x * 256 + threadIdx.x;
    if (i >= 1536) return;
    int h = i >> 9, b = i & 511;
    float bias = (h == 0) ? b3e[0] : (h == 1) ? b3m[0] : b3c[0];
    float z = headacc[b * 3 + h] + bias;
    out[i] = 1.f / (1.f + __expf(-z));
}

extern "C" void kernel_launch(void* const* d_in, const int* in_sizes, int n_in,
                              void* d_out, int out_size, void* d_ws, size_t ws_size,
                              hipStream_t stream) {
    const float* Ae  = (const float*)d_in[0];
    const float* Am  = (const float*)d_in[1];
    const float* Ac  = (const float*)d_in[2];
    const float* Wex = (const float*)d_in[3];
    const float* Wey = (const float*)d_in[4];
    const float* Wmx = (const float*)d_in[5];
    const float* Wmy = (const float*)d_in[6];
    const float* Wcx = (const float*)d_in[7];
    const float* Wcy = (const float*)d_in[8];
    const float* W3e = (const float*)d_in[9];
    const float* b3e = (const float*)d_in[10];
    const float* W3m = (const float*)d_in[11];
    const float* b3m = (const float*)d_in[12];
    const float* W3c = (const float*)d_in[13];
    const float* b3c = (const float*)d_in[14];

    // workspace: part[48][nsplit][16384] | P[786432] | headacc[1536]
    size_t fixed = (size_t)786432 * 4 + 1536 * 4;
    int nsplit = 2;
    if (ws_size > fixed) {
        size_t avail = (ws_size - fixed) / ((size_t)48 * 16384 * 4);
        nsplit = (avail < MAXSPLIT) ? (int)avail : MAXSPLIT;
        if (nsplit < 1) nsplit = 1;
    }

    float* part    = (float*)d_ws;
    float* P       = part + (size_t)48 * nsplit * 16384;
    float* headacc = P + 786432;

    gemm_kernel<<<48 * nsplit, 256, 0, stream>>>(Ae, Am, Ac, Wex, Wey, Wmx, Wmy, Wcx, Wcy,
                                                 part, nsplit);
    reduce_kernel<<<3072, 256, 0, stream>>>(part, P, headacc, nsplit);
    pairs_kernel<<<1536, 256, 0, stream>>>(P, headacc, W3e, W3m, W3c);
    head_kernel<<<6, 256, 0, stream>>>(headacc, b3e, b3m, b3c, (float*)d_out);
}